// Round 7
// baseline (128.583 us; speedup 1.0000x reference)
//
#include <hip/hip_runtime.h>

// SINDy: out[65536,32] = Theta(z)[65536,6545] @ (Xi*Xi_mask)[6545,32]
// Round-24: occupancy x2 — 32-row blocks, 2048 blocks, 8 waves/SIMD.
//  - R23 post-mortem: depth-2 prefetch worked (60->46us). Remaining wall:
//    true MFMA pipe ~8%, VALU issue 38%, mem ~4% -> ~50% issue slots IDLE
//    = latency-bound at 4 waves/SIMD (Occupancy 28.5%).
//  - Fix: halve row-tile (1 tile/wave), double grid -> 8 blocks/CU =
//    8 waves/SIMD. VGPR drops (acc 16 regs, z-octets 4); LDS 12.8KB/block
//    (zs[33][32] + cs[32][32] + mg 4.5KB) x8 = 102KB < 160KB.
//    __launch_bounds__(256,8) caps VGPR at 64 (we're under).
//  - Cost: B L2 traffic x2 (6.3 TB/s << 34.5 ceiling); HBM unchanged.
//  - mg table rebuilt for 128B k-stride (zs[k][32], offs i*128|j*128<<16;
//    pad i=32 -> zs[32][m]=1.0).
// MFMA 32x32x16 layouts (dtype-independent, verified rounds 1-14):
//   A[m][k]: m=lane&31, k=(lane>>5)*8+jj   (reg q: lo=k 2q, hi=k 2q+1)
//   B[k][n]: n=lane&31, k=(lane>>5)*8+jj
//   C/D:     col=lane&31, row=(reg&3)+8*(reg>>2)+4*(lane>>5)

#define Z 32
#define ROWS 65536
#define NBLK (ROWS / 32)         // 2048 blocks: 1 tile x 4 k-splits (4 waves)

#define NCHUNK 552               // quarters: 36 + 84 + 160 + 272
#define NGRAN (NCHUNK * 2)
#define NGP 1120                 // padded mg table (overreads -> 0)
#define KSPAN 138                // chunks per k-split (552/4)

typedef float f32x16 __attribute__((ext_vector_type(16)));
typedef _Float16 h2 __attribute__((ext_vector_type(2)));
typedef _Float16 h8 __attribute__((ext_vector_type(8)));

// cvt_pkrtz returns __fp16x2 — bit_cast to the _Float16 vector world
__device__ __forceinline__ h2 pkrtz(float a, float b) {
    return __builtin_bit_cast(h2, __builtin_amdgcn_cvt_pkrtz(a, b));
}

struct Sched {
    unsigned mg[NGP];          // (i*128) | (j*128)<<16 byte offs into zs[k][32]; pad=0
    short rt[NGRAN * 8];       // library row per (granule, jj), -1 = pad
    int nq[4];
};

constexpr Sched make_sched() {
    Sched s{};
    short gi[NGP] = {}, gj[NGP] = {};
    char gt[NGP] = {}, gq[NGP] = {};
    int tidx[32][32] = {}, pidx[32] = {};
    {
        int n = 0;
        for (int a = 0; a < 32; ++a)
            for (int b = a; b < 32; ++b) { tidx[a][b] = n; n += 32 - b; }
        for (int i = 0; i < 32; ++i) pidx[i] = i * 32 - i * (i - 1) / 2;
    }
    int g = 0;
    for (int q = 0; q < 4; ++q) {
        int g0 = g;
        // triples (a<=b): granule covers k in [8q,8q+8) for k>=b -> b>>3 <= q
        for (int b = 0; b < 32; ++b)
            if ((b >> 3) <= q)
                for (int a = 0; a <= b; ++a) { gi[g]=(short)a; gj[g]=(short)b; gt[g]=0; gq[g]=(char)q; ++g; }
        // pairs (b,32): theta = z_b*z_k, valid k<=b -> b>>3 >= q
        for (int b = 0; b < 32; ++b)
            if ((b >> 3) >= q) { gi[g]=(short)b; gj[g]=32; gt[g]=1; gq[g]=(char)q; ++g; }
        // linear: theta = z_k
        gi[g]=32; gj[g]=32; gt[g]=2; gq[g]=(char)q; ++g;
        // pad quarter to a multiple of 8 granules (4 chunks)
        while ((g - g0) & 7) { gi[g]=32; gj[g]=32; gt[g]=3; gq[g]=(char)q; ++g; }
        s.nq[q] = (g - g0) / 2;
    }
    for (int gg = 0; gg < NGRAN; ++gg) {
        s.mg[gg] = ((unsigned)gi[gg] * 128u) | (((unsigned)gj[gg] * 128u) << 16);
        int i = gi[gg], j = gj[gg], ty = gt[gg], q = gq[gg];
        for (int jj = 0; jj < 8; ++jj) {
            int k = 8 * q + jj, row = -1;
            if (ty == 0)      { if (k >= j) row = 561 + tidx[i][j] + (k - j); }   // triple (i,j,k)
            else if (ty == 1) { if (k <= i) row = 33 + pidx[k] + (i - k); }       // pair (k,i)
            else if (ty == 2) { row = 1 + k; }                                    // linear z_k
            s.rt[gg * 8 + jj] = (short)row;
        }
    }
    // [NGRAN,NGP): mg stays 0 -> pipeline overreads hit zs[0][m], never used
    return s;
}
constexpr Sched S = make_sched();
static_assert(S.nq[0] == 36 && S.nq[1] == 84 && S.nq[2] == 160 && S.nq[3] == 272, "chunk counts");

// ---- prep (R7-proven structure): coalesced, block per 4 granules; B -> fp16 RNE ----
__global__ void sindy_prep(const float* __restrict__ Xi,
                           const float* __restrict__ Xi_mask,
                           uint2* __restrict__ Bp2, size_t ws_size) {
    __shared__ unsigned short sh[8][32];
    const int tid = threadIdx.x;
    const int jj = tid >> 5, n = tid & 31;
#pragma unroll
    for (int pass = 0; pass < 4; ++pass) {
        int g = blockIdx.x * 4 + pass;
        int row = S.rt[g * 8 + jj];
        float f = 0.0f;
        if (row >= 0) f = Xi[row * Z + n] * Xi_mask[row * Z + n];
        _Float16 hh = (_Float16)f;                       // RNE f32->f16
        sh[jj][n] = __builtin_bit_cast(unsigned short, hh);
        __syncthreads();
        if (tid < 64) {
            int n2 = tid & 31, rep = tid >> 5;
            unsigned v0 = sh[4*rep+0][n2], v1 = sh[4*rep+1][n2];
            unsigned v2 = sh[4*rep+2][n2], v3 = sh[4*rep+3][n2];
            int c = g >> 1, h = g & 1;
            size_t idx = ((size_t)c * 64 + h * 32 + n2) * 2 + rep;
            if ((idx + 1) * 8 <= ws_size)
                Bp2[idx] = uint2{v0 | (v1 << 16), v2 | (v3 << 16)};
        }
        __syncthreads();
    }
}

// ---- main: block = 1 tile (32 rows) x 4 k-splits; 8 blocks/CU ----
__global__ __launch_bounds__(256, 8) void sindy_mfma(const float* __restrict__ z,
                                                     const float* __restrict__ Xi,
                                                     const float* __restrict__ Xi_mask,
                                                     const uint4* __restrict__ Bp,
                                                     float* __restrict__ out) {
    const int lane = threadIdx.x & 63;
    const int kh = threadIdx.x >> 6;     // k-split 0..3 (= wave id)
    const int m = lane & 31;
    const int half = lane >> 5;
    const long R = (long)blockIdx.x * 32;   // 32 rows per block

    __shared__ float zs[33][32];         // zs[k][m]; k stride 128B; bank = m
    __shared__ float cs[32][32];         // sequential-add combine
    __shared__ unsigned mg_sh[NGP];

    for (int t = threadIdx.x; t < NGP; t += 256) mg_sh[t] = S.mg[t];
    // stage z for 32 rows (coalesced float4 reads): 256 float4 = 256 threads
    {
        int row = threadIdx.x >> 3, q4 = threadIdx.x & 7;
        float4 v = ((const float4*)(z + (R + row) * Z))[q4];
        zs[4*q4+0][row] = v.x; zs[4*q4+1][row] = v.y;
        zs[4*q4+2][row] = v.z; zs[4*q4+3][row] = v.w;
    }
    if (threadIdx.x < 32) zs[32][threadIdx.x] = 1.0f;   // z~[32] = 1
    __syncthreads();

    const int c0 = kh * KSPAN;
    const char* zmb = (const char*)&zs[0][0] + 4 * m;
    const unsigned* mgh = mg_sh + half;
    const uint4* bpl = Bp + lane;

    // B register pipeline, depth 2: b0* = pair consumed this body,
    // b1* = pair for the next body; loads issue 2 bodies ahead.
    uint4 b0A = bpl[(size_t)(c0 + 0) * 64];
    uint4 b0B = bpl[(size_t)(c0 + 1) * 64];
    uint4 b1A = bpl[(size_t)(c0 + 2) * 64];
    uint4 b1B = bpl[(size_t)(c0 + 3) * 64];

    // marching pointers (strength-reduced; no clamps in the loop)
    const uint4* bptr = bpl + (size_t)(c0 + 4) * 64;   // chunk c+4; c+5 at +1024B imm
    const unsigned* mgp = mgh + 2 * c0 + 8;            // mg for body+2; pair 8B apart

    // prime shallow pipeline (plain scalars, single scope — R9/R13-proven)
    unsigned u0 = mgh[2*c0], u1 = mgh[2*c0+2];
    float pA, pB;
    {
        float i0 = *(const float*)(zmb + (u0 & 0xFFFFu));
        float j0 = *(const float*)(zmb + (u0 >> 16));
        pA = i0 * j0;
        float e0 = *(const float*)(zmb + (u1 & 0xFFFFu));
        float f0 = *(const float*)(zmb + (u1 >> 16));
        pB = e0 * f0;
    }
    unsigned w0s = mgh[2*c0+4], w1s = mgh[2*c0+6];

    f32x16 acc = {};

    auto seg = [&](int Q, int cbeg, int cfin, bool tail) {
        // this quarter's z octet, pre-packed to fp16 pairs (RTZ).
        // reg q: lo = k 2q, hi = k 2q+1; k stride 128B.
        const char* zq = zmb + Q * 1024;
        h2 z0, z1, z2, z3;
        {
            float a0 = *(const float*)(zq +   0), a1 = *(const float*)(zq + 128);
            float a2 = *(const float*)(zq + 256), a3 = *(const float*)(zq + 384);
            float a4 = *(const float*)(zq + 512), a5 = *(const float*)(zq + 640);
            float a6 = *(const float*)(zq + 768), a7 = *(const float*)(zq + 896);
            z0 = pkrtz(a0, a1); z1 = pkrtz(a2, a3);
            z2 = pkrtz(a4, a5); z3 = pkrtz(a6, a7);
        }

        auto domfma = [&](float pp, const uint4& bv) {
            h2 p2 = pkrtz(pp, pp);
            union { h2 h[4]; h8 v; } a;
            a.h[0] = p2 * z0; a.h[1] = p2 * z1;
            a.h[2] = p2 * z2; a.h[3] = p2 * z3;
            union { uint4 v; h8 h; } b; b.v = bv;
            acc = __builtin_amdgcn_mfma_f32_32x32x16_f16(a.v, b.h, acc, 0, 0, 0);
        };

        const int cend = tail ? cfin - 4 : cfin;
#pragma unroll 2
        for (int c = cbeg; c < cend; c += 2) {
            // top: issue loads for pair (c+4, c+5) — 2 bodies ahead. Marching
            // pointer; 2nd load folds to imm offset:1024. kh3's last loads
            // land exactly on chunks 550/551 (tail bodies are peeled).
            uint4 nA = bptr[0];
            uint4 nB = bptr[64];
            bptr += 128;
            // stage 1: mg for body+2 (pad absorbs overread)
            unsigned nw0 = mgp[0], nw1 = mgp[2];
            mgp += 4;
            // stage 2: z reads for body+1's products
            float ai = *(const float*)(zmb + (w0s & 0xFFFFu));
            float aj = *(const float*)(zmb + (w0s >> 16));
            float bi = *(const float*)(zmb + (w1s & 0xFFFFu));
            float bj = *(const float*)(zmb + (w1s >> 16));
            // 2 MFMAs: 2 chunks x 1 tile
            domfma(pA, b0A);
            domfma(pB, b0B);
            // retire products + mg + rotate B pipeline
            pA = ai * aj; pB = bi * bj;
            w0s = nw0; w1s = nw1;
            b0A = b1A; b0B = b1B; b1A = nA; b1B = nB;
        }
        if (tail) {
            // peel body cfin-4 (chunks 548/549): no B loads; KEEP z staging
            float ai = *(const float*)(zmb + (w0s & 0xFFFFu));
            float aj = *(const float*)(zmb + (w0s >> 16));
            float bi = *(const float*)(zmb + (w1s & 0xFFFFu));
            float bj = *(const float*)(zmb + (w1s >> 16));
            domfma(pA, b0A);
            domfma(pB, b0B);
            pA = ai * aj; pB = bi * bj;
            b0A = b1A; b0B = b1B;
            // peel final body cfin-2 (chunks 550/551): consume-only
            domfma(pA, b0A);
            domfma(pB, b0B);
        }
    };

    // quarter-aligned pieces of this wave's [c0, c0+138) range
    if (kh == 0)      { seg(0,   0,  36, false); seg(1,  36, 120, false); seg(2, 120, 138, false); }
    else if (kh == 1) { seg(2, 138, 276, false); }
    else if (kh == 2) { seg(2, 276, 280, false); seg(3, 280, 414, false); }
    else              { seg(3, 414, 552, true); }

    // sequential-add combine: kh3 writes, kh2/kh1 add, kh0 finishes
    if (kh == 3) {
#pragma unroll
        for (int r = 0; r < 16; ++r) {
            int row = (r & 3) + 8 * (r >> 2) + 4 * half;
            cs[row][m] = acc[r];
        }
    }
    __syncthreads();
    if (kh == 2) {
#pragma unroll
        for (int r = 0; r < 16; ++r) {
            int row = (r & 3) + 8 * (r >> 2) + 4 * half;
            cs[row][m] += acc[r];
        }
    }
    __syncthreads();
    if (kh == 1) {
#pragma unroll
        for (int r = 0; r < 16; ++r) {
            int row = (r & 3) + 8 * (r >> 2) + 4 * half;
            cs[row][m] += acc[r];
        }
    }
    __syncthreads();
    if (kh == 0) {
        const float bias = Xi[m] * Xi_mask[m];   // library row 0 (ones), col n = m
        float* o0 = out + R * Z;
#pragma unroll
        for (int r = 0; r < 16; ++r) {
            int row = (r & 3) + 8 * (r >> 2) + 4 * half;
            o0[row * Z + m] = acc[r] + cs[row][m] + bias;
        }
    }
}

extern "C" void kernel_launch(void* const* d_in, const int* in_sizes, int n_in,
                              void* d_out, int out_size, void* d_ws, size_t ws_size,
                              hipStream_t stream) {
    const float* z       = (const float*)d_in[0];
    const float* Xi      = (const float*)d_in[1];
    const float* Xi_mask = (const float*)d_in[2];
    // d_in[3]=z_mean, d_in[4]=z_std: unused by the reference
    float* out = (float*)d_out;
    uint4* Bp  = (uint4*)d_ws;   // NCHUNK*64*16 = 565,248 bytes

    sindy_prep<<<NGRAN / 4, 256, 0, stream>>>(Xi, Xi_mask, (uint2*)d_ws, ws_size);
    sindy_mfma<<<NBLK, 256, 0, stream>>>(z, Xi, Xi_mask, Bp, out);
}

// Round 8
// 111.755 us; speedup vs baseline: 1.1506x; 1.1506x over previous
//
#include <hip/hip_runtime.h>

// SINDy: out[65536,32] = Theta(z)[65536,6545] @ (Xi*Xi_mask)[6545,32]
// Round-25: revert to R23 shell (64-row, 4 waves), 4-chunk / 8-MFMA bodies.
//  - R24 post-mortem: occupancy x2 regressed (46->66us, both pipes LESS
//    busy). Halving the tile doubled B/L2 traffic + VMEM inst rate and
//    halved work per fixed body overhead. Occupancy was not the binding
//    constraint; work-per-transaction was.
//  - This round: bigger bodies on the R23 winner. 4 chunks (8 MFMA) per
//    body amortizes loads/mg/pointer/rotation overhead: ~19 -> ~9-10 VALU
//    insts per MFMA. Chip VALU work ~8.6us < MFMA floor 14.7us -> enters
//    MFMA-bound regime. Prefetch depth still 2 bodies = 8 chunks in
//    flight (MORE latency cover, not less). B traffic = R23 (unchanged).
//  - K-split re-cut to 136/136/140/140 chunks (quarter-aligned, all
//    segments %4==0): w0=[0,136) w1=[136,272) w2=[272,412) w3=[412,552).
//    w3 peels last TWO bodies; in-loop loads end exactly at chunk 551.
// MFMA 32x32x16 layouts (dtype-independent, verified rounds 1-14):
//   A[m][k]: m=lane&31, k=(lane>>5)*8+jj   (reg q: lo=k 2q, hi=k 2q+1)
//   B[k][n]: n=lane&31, k=(lane>>5)*8+jj
//   C/D:     col=lane&31, row=(reg&3)+8*(reg>>2)+4*(lane>>5)

#define Z 32
#define ROWS 65536
#define NBLK (ROWS / 64)         // 1024 blocks: 2 tiles x 4 k-splits (4 waves)

#define NCHUNK 552               // quarters: 36 + 84 + 160 + 272
#define NGRAN (NCHUNK * 2)
#define NGP 1120                 // padded mg table (overreads -> 0)

typedef float f32x16 __attribute__((ext_vector_type(16)));
typedef _Float16 h2 __attribute__((ext_vector_type(2)));
typedef _Float16 h8 __attribute__((ext_vector_type(8)));

// cvt_pkrtz returns __fp16x2 — bit_cast to the _Float16 vector world
__device__ __forceinline__ h2 pkrtz(float a, float b) {
    return __builtin_bit_cast(h2, __builtin_amdgcn_cvt_pkrtz(a, b));
}

struct Sched {
    unsigned mg[NGP];          // (i*256) | (j*256)<<16 byte offs into zs[k][2][32]; pad=0
    short rt[NGRAN * 8];       // library row per (granule, jj), -1 = pad
    int nq[4];
};

constexpr Sched make_sched() {
    Sched s{};
    short gi[NGP] = {}, gj[NGP] = {};
    char gt[NGP] = {}, gq[NGP] = {};
    int tidx[32][32] = {}, pidx[32] = {};
    {
        int n = 0;
        for (int a = 0; a < 32; ++a)
            for (int b = a; b < 32; ++b) { tidx[a][b] = n; n += 32 - b; }
        for (int i = 0; i < 32; ++i) pidx[i] = i * 32 - i * (i - 1) / 2;
    }
    int g = 0;
    for (int q = 0; q < 4; ++q) {
        int g0 = g;
        // triples (a<=b): granule covers k in [8q,8q+8) for k>=b -> b>>3 <= q
        for (int b = 0; b < 32; ++b)
            if ((b >> 3) <= q)
                for (int a = 0; a <= b; ++a) { gi[g]=(short)a; gj[g]=(short)b; gt[g]=0; gq[g]=(char)q; ++g; }
        // pairs (b,32): theta = z_b*z_k, valid k<=b -> b>>3 >= q
        for (int b = 0; b < 32; ++b)
            if ((b >> 3) >= q) { gi[g]=(short)b; gj[g]=32; gt[g]=1; gq[g]=(char)q; ++g; }
        // linear: theta = z_k
        gi[g]=32; gj[g]=32; gt[g]=2; gq[g]=(char)q; ++g;
        // pad quarter to a multiple of 8 granules (4 chunks)
        while ((g - g0) & 7) { gi[g]=32; gj[g]=32; gt[g]=3; gq[g]=(char)q; ++g; }
        s.nq[q] = (g - g0) / 2;
    }
    for (int gg = 0; gg < NGRAN; ++gg) {
        s.mg[gg] = ((unsigned)gi[gg] * 256u) | (((unsigned)gj[gg] * 256u) << 16);
        int i = gi[gg], j = gj[gg], ty = gt[gg], q = gq[gg];
        for (int jj = 0; jj < 8; ++jj) {
            int k = 8 * q + jj, row = -1;
            if (ty == 0)      { if (k >= j) row = 561 + tidx[i][j] + (k - j); }   // triple (i,j,k)
            else if (ty == 1) { if (k <= i) row = 33 + pidx[k] + (i - k); }       // pair (k,i)
            else if (ty == 2) { row = 1 + k; }                                    // linear z_k
            s.rt[gg * 8 + jj] = (short)row;
        }
    }
    // [NGRAN,NGP): mg stays 0 -> pipeline overreads hit zs[0][0][m], never used
    return s;
}
constexpr Sched S = make_sched();
static_assert(S.nq[0] == 36 && S.nq[1] == 84 && S.nq[2] == 160 && S.nq[3] == 272, "chunk counts");

// ---- prep (R7-proven structure): coalesced, block per 4 granules; B -> fp16 RNE ----
__global__ void sindy_prep(const float* __restrict__ Xi,
                           const float* __restrict__ Xi_mask,
                           uint2* __restrict__ Bp2, size_t ws_size) {
    __shared__ unsigned short sh[8][32];
    const int tid = threadIdx.x;
    const int jj = tid >> 5, n = tid & 31;
#pragma unroll
    for (int pass = 0; pass < 4; ++pass) {
        int g = blockIdx.x * 4 + pass;
        int row = S.rt[g * 8 + jj];
        float f = 0.0f;
        if (row >= 0) f = Xi[row * Z + n] * Xi_mask[row * Z + n];
        _Float16 hh = (_Float16)f;                       // RNE f32->f16
        sh[jj][n] = __builtin_bit_cast(unsigned short, hh);
        __syncthreads();
        if (tid < 64) {
            int n2 = tid & 31, rep = tid >> 5;
            unsigned v0 = sh[4*rep+0][n2], v1 = sh[4*rep+1][n2];
            unsigned v2 = sh[4*rep+2][n2], v3 = sh[4*rep+3][n2];
            int c = g >> 1, h = g & 1;
            size_t idx = ((size_t)c * 64 + h * 32 + n2) * 2 + rep;
            if ((idx + 1) * 8 <= ws_size)
                Bp2[idx] = uint2{v0 | (v1 << 16), v2 | (v3 << 16)};
        }
        __syncthreads();
    }
}

// ---- main: block = 2 tiles x 4 k-splits; wave = BOTH tiles, one k-split ----
__global__ __launch_bounds__(256, 4) void sindy_mfma(const float* __restrict__ z,
                                                     const float* __restrict__ Xi,
                                                     const float* __restrict__ Xi_mask,
                                                     const uint4* __restrict__ Bp,
                                                     float* __restrict__ out) {
    const int lane = threadIdx.x & 63;
    const int kh = threadIdx.x >> 6;     // k-split 0..3 (= wave id)
    const int m = lane & 31;
    const int half = lane >> 5;
    const long R = (long)blockIdx.x * 64;   // rows of tile0; tile1 = R+32

    __shared__ float zs[33][2][32];      // interleaved: zs[k][tile][m]; bank = m
    __shared__ float cs[2][32][32];      // sequential-add combine (2 tiles)
    __shared__ unsigned mg_sh[NGP];

    for (int t = threadIdx.x; t < NGP; t += 256) mg_sh[t] = S.mg[t];
    // stage z for 64 rows (coalesced float4 reads)
    for (int idx = threadIdx.x; idx < 512; idx += 256) {
        int row = idx >> 3, q4 = idx & 7;
        float4 v = ((const float4*)(z + (R + row) * Z))[q4];
        int t = row >> 5, mm = row & 31;
        zs[4*q4+0][t][mm] = v.x; zs[4*q4+1][t][mm] = v.y;
        zs[4*q4+2][t][mm] = v.z; zs[4*q4+3][t][mm] = v.w;
    }
    if (threadIdx.x < 64) zs[32][threadIdx.x >> 5][threadIdx.x & 31] = 1.0f;  // z~[32]=1
    __syncthreads();

    // k-split cut points: all segments quarter-aligned and %4 chunks
    const int c0 = (kh == 0) ? 0 : (kh == 1) ? 136 : (kh == 2) ? 272 : 412;
    const char* zmb = (const char*)&zs[0][0][0] + 4 * m;   // tile0; tile1 = +128
    const unsigned* mgh = mg_sh + half;
    const uint4* bpl = Bp + lane;

    // helper: z-pair products for one mg word (both tiles)
    auto zprod = [&](unsigned ws, float& t0, float& t1) {
        float i0 = *(const float*)(zmb + (ws & 0xFFFFu));
        float i1 = *(const float*)(zmb + (ws & 0xFFFFu) + 128);
        float j0 = *(const float*)(zmb + (ws >> 16));
        float j1 = *(const float*)(zmb + (ws >> 16) + 128);
        t0 = i0 * j0; t1 = i1 * j1;
    };

    // B register pipeline, depth 2 bodies x 4 chunks (8 chunks in flight)
    uint4 b00 = bpl[(size_t)(c0 + 0) * 64], b01 = bpl[(size_t)(c0 + 1) * 64];
    uint4 b02 = bpl[(size_t)(c0 + 2) * 64], b03 = bpl[(size_t)(c0 + 3) * 64];
    uint4 b10 = bpl[(size_t)(c0 + 4) * 64], b11 = bpl[(size_t)(c0 + 5) * 64];
    uint4 b12 = bpl[(size_t)(c0 + 6) * 64], b13 = bpl[(size_t)(c0 + 7) * 64];

    // marching pointers (strength-reduced; no clamps in the loop)
    const uint4* bptr = bpl + (size_t)(c0 + 8) * 64;   // chunk c+8..c+11 (imm 0/1024/2048/3072)
    const unsigned* mgp = mgh + 2 * c0 + 16;           // mg for body+2

    // prime: products for chunks c0..c0+3, mg words for c0+4..c0+7
    float p00, p01, p10, p11, p20, p21, p30, p31;
    {
        unsigned u0 = mgh[2*c0+0], u1 = mgh[2*c0+2];
        unsigned u2 = mgh[2*c0+4], u3 = mgh[2*c0+6];
        zprod(u0, p00, p01); zprod(u1, p10, p11);
        zprod(u2, p20, p21); zprod(u3, p30, p31);
    }
    unsigned w0s = mgh[2*c0+ 8], w1s = mgh[2*c0+10];
    unsigned w2s = mgh[2*c0+12], w3s = mgh[2*c0+14];

    f32x16 acc0 = {}, acc1 = {};

    auto seg = [&](int Q, int cbeg, int cfin, bool tail) {
        // this quarter's z octets for both tiles, pre-packed to fp16 pairs
        // (RTZ). reg q: lo=k 2q, hi=k 2q+1; k stride 256B (interleaved tiles).
        const char* zq = zmb + Q * 2048;
        h2 zA0, zA1, zA2, zA3, zB0, zB1, zB2, zB3;
        {
            float a0 = *(const float*)(zq +    0), a1 = *(const float*)(zq +  256);
            float a2 = *(const float*)(zq +  512), a3 = *(const float*)(zq +  768);
            float a4 = *(const float*)(zq + 1024), a5 = *(const float*)(zq + 1280);
            float a6 = *(const float*)(zq + 1536), a7 = *(const float*)(zq + 1792);
            float b0 = *(const float*)(zq +  128), b1 = *(const float*)(zq +  384);
            float b2 = *(const float*)(zq +  640), b3 = *(const float*)(zq +  896);
            float b4 = *(const float*)(zq + 1152), b5 = *(const float*)(zq + 1408);
            float b6 = *(const float*)(zq + 1664), b7 = *(const float*)(zq + 1920);
            zA0 = pkrtz(a0, a1); zA1 = pkrtz(a2, a3);
            zA2 = pkrtz(a4, a5); zA3 = pkrtz(a6, a7);
            zB0 = pkrtz(b0, b1); zB1 = pkrtz(b2, b3);
            zB2 = pkrtz(b4, b5); zB3 = pkrtz(b6, b7);
        }

        auto mfma0 = [&](float pp, const uint4& bv) {   // tile0
            h2 p2 = pkrtz(pp, pp);
            union { h2 h[4]; h8 v; } a;
            a.h[0] = p2 * zA0; a.h[1] = p2 * zA1;
            a.h[2] = p2 * zA2; a.h[3] = p2 * zA3;
            union { uint4 v; h8 h; } b; b.v = bv;
            acc0 = __builtin_amdgcn_mfma_f32_32x32x16_f16(a.v, b.h, acc0, 0, 0, 0);
        };
        auto mfma1 = [&](float pp, const uint4& bv) {   // tile1
            h2 p2 = pkrtz(pp, pp);
            union { h2 h[4]; h8 v; } a;
            a.h[0] = p2 * zB0; a.h[1] = p2 * zB1;
            a.h[2] = p2 * zB2; a.h[3] = p2 * zB3;
            union { uint4 v; h8 h; } b; b.v = bv;
            acc1 = __builtin_amdgcn_mfma_f32_32x32x16_f16(a.v, b.h, acc1, 0, 0, 0);
        };

        const int cend = tail ? cfin - 8 : cfin;
#pragma unroll 2
        for (int c = cbeg; c < cend; c += 4) {
            // top: issue loads for chunks c+8..c+11 — 2 bodies ahead.
            // Imm offsets 0/1024/2048/3072; one pointer march per body.
            uint4 n0 = bptr[0], n1 = bptr[64], n2 = bptr[128], n3 = bptr[192];
            bptr += 256;
            // mg for body+2 (pad absorbs overread)
            unsigned nw0 = mgp[0], nw1 = mgp[2], nw2 = mgp[4], nw3 = mgp[6];
            mgp += 8;
            // z reads + products for body+1 (8 scalars, ds_read2 pairs)
            float q00, q01, q10, q11, q20, q21, q30, q31;
            zprod(w0s, q00, q01); zprod(w1s, q10, q11);
            zprod(w2s, q20, q21); zprod(w3s, q30, q31);
            // 8 MFMAs: 4 chunks x 2 tiles, B shared per chunk
            mfma0(p00, b00); mfma1(p01, b00);
            mfma0(p10, b01); mfma1(p11, b01);
            mfma0(p20, b02); mfma1(p21, b02);
            mfma0(p30, b03); mfma1(p31, b03);
            // retire products + mg + rotate B pipeline
            p00 = q00; p01 = q01; p10 = q10; p11 = q11;
            p20 = q20; p21 = q21; p30 = q30; p31 = q31;
            w0s = nw0; w1s = nw1; w2s = nw2; w3s = nw3;
            b00 = b10; b01 = b11; b02 = b12; b03 = b13;
            b10 = n0;  b11 = n1;  b12 = n2;  b13 = n3;
        }
        if (tail) {
            // peel body cfin-8 (chunks 544-547): no loads/mg; KEEP z staging
            float q00, q01, q10, q11, q20, q21, q30, q31;
            zprod(w0s, q00, q01); zprod(w1s, q10, q11);
            zprod(w2s, q20, q21); zprod(w3s, q30, q31);
            mfma0(p00, b00); mfma1(p01, b00);
            mfma0(p10, b01); mfma1(p11, b01);
            mfma0(p20, b02); mfma1(p21, b02);
            mfma0(p30, b03); mfma1(p31, b03);
            p00 = q00; p01 = q01; p10 = q10; p11 = q11;
            p20 = q20; p21 = q21; p30 = q30; p31 = q31;
            b00 = b10; b01 = b11; b02 = b12; b03 = b13;
            // peel final body cfin-4 (chunks 548-551): consume-only
            mfma0(p00, b00); mfma1(p01, b00);
            mfma0(p10, b01); mfma1(p11, b01);
            mfma0(p20, b02); mfma1(p21, b02);
            mfma0(p30, b03); mfma1(p31, b03);
        }
    };

    // quarter-aligned pieces of this wave's k-range (all %4 chunks)
    if (kh == 0)      { seg(0,   0,  36, false); seg(1,  36, 120, false); seg(2, 120, 136, false); }
    else if (kh == 1) { seg(2, 136, 272, false); }
    else if (kh == 2) { seg(2, 272, 280, false); seg(3, 280, 412, false); }
    else              { seg(3, 412, 552, true); }

    // sequential-add combine: kh3 writes, kh2/kh1 add, kh0 finishes
    if (kh == 3) {
#pragma unroll
        for (int r = 0; r < 16; ++r) {
            int row = (r & 3) + 8 * (r >> 2) + 4 * half;
            cs[0][row][m] = acc0[r]; cs[1][row][m] = acc1[r];
        }
    }
    __syncthreads();
    if (kh == 2) {
#pragma unroll
        for (int r = 0; r < 16; ++r) {
            int row = (r & 3) + 8 * (r >> 2) + 4 * half;
            cs[0][row][m] += acc0[r]; cs[1][row][m] += acc1[r];
        }
    }
    __syncthreads();
    if (kh == 1) {
#pragma unroll
        for (int r = 0; r < 16; ++r) {
            int row = (r & 3) + 8 * (r >> 2) + 4 * half;
            cs[0][row][m] += acc0[r]; cs[1][row][m] += acc1[r];
        }
    }
    __syncthreads();
    if (kh == 0) {
        const float bias = Xi[m] * Xi_mask[m];   // library row 0 (ones), col n = m
        float* o0 = out + R * Z;
        float* o1 = out + (R + 32) * Z;
#pragma unroll
        for (int r = 0; r < 16; ++r) {
            int row = (r & 3) + 8 * (r >> 2) + 4 * half;
            o0[row * Z + m] = acc0[r] + cs[0][row][m] + bias;
            o1[row * Z + m] = acc1[r] + cs[1][row][m] + bias;
        }
    }
}

extern "C" void kernel_launch(void* const* d_in, const int* in_sizes, int n_in,
                              void* d_out, int out_size, void* d_ws, size_t ws_size,
                              hipStream_t stream) {
    const float* z       = (const float*)d_in[0];
    const float* Xi      = (const float*)d_in[1];
    const float* Xi_mask = (const float*)d_in[2];
    // d_in[3]=z_mean, d_in[4]=z_std: unused by the reference
    float* out = (float*)d_out;
    uint4* Bp  = (uint4*)d_ws;   // NCHUNK*64*16 = 565,248 bytes

    sindy_prep<<<NGRAN / 4, 256, 0, stream>>>(Xi, Xi_mask, (uint2*)d_ws, ws_size);
    sindy_mfma<<<NBLK, 256, 0, stream>>>(z, Xi, Xi_mask, Bp, out);
}

// Round 9
// 109.499 us; speedup vs baseline: 1.1743x; 1.0206x over previous
//
#include <hip/hip_runtime.h>

// SINDy: out[65536,32] = Theta(z)[65536,6545] @ (Xi*Xi_mask)[6545,32]
// Round-26: 4 row-tiles per wave (128-row blocks, grid 512).
//  - R25 post-mortem: three equal ~16us components (VALU 17, MFMA 16,
//    B L2-stream 578MB~17) SUM to the 47us wall. R24 showed traffic x2
//    -> wall 66; so cut traffic AND per-MFMA VALU together:
//  - Each wave now owns 4 tiles (128 rows). B chunk / mg word / pointer
//    march amortize over 4 MFMAs: ~18 -> ~8 VALU/MFMA. B traffic halves
//    (2048 waves -> 1024... grid 512 x 4 waves x 138KB = 289MB ~ 8us).
//    4 independent acc chains break the acc RAW chain.
//  - Occupancy: grid-limited 2 blocks/CU (2 waves/SIMD). launch_bounds
//    (256,2) -> VGPR cap 256, no spill (est ~140).
//  - k-split cuts back to R17's [0,138,276,414,552) (segments all even:
//    36/84/18 | 138 | 4/134 | 138). Body = 2 chunks x 4 tiles = 8 MFMA.
//    Depth-2 prefetch (4 chunks in flight). kh3 peels last 2 bodies.
// MFMA 32x32x16 layouts (dtype-independent, verified rounds 1-14):
//   A[m][k]: m=lane&31, k=(lane>>5)*8+jj   (reg q: lo=k 2q, hi=k 2q+1)
//   B[k][n]: n=lane&31, k=(lane>>5)*8+jj
//   C/D:     col=lane&31, row=(reg&3)+8*(reg>>2)+4*(lane>>5)

#define Z 32
#define ROWS 65536
#define NBLK (ROWS / 128)        // 512 blocks: 4 tiles x 4 k-splits (4 waves)

#define NCHUNK 552               // quarters: 36 + 84 + 160 + 272
#define NGRAN (NCHUNK * 2)
#define NGP 1120                 // padded mg table (overreads -> 0)

typedef float f32x16 __attribute__((ext_vector_type(16)));
typedef _Float16 h2 __attribute__((ext_vector_type(2)));
typedef _Float16 h8 __attribute__((ext_vector_type(8)));

// cvt_pkrtz returns __fp16x2 — bit_cast to the _Float16 vector world
__device__ __forceinline__ h2 pkrtz(float a, float b) {
    return __builtin_bit_cast(h2, __builtin_amdgcn_cvt_pkrtz(a, b));
}

struct Sched {
    unsigned mg[NGP];          // (i*512) | (j*512)<<16 byte offs into zs[k][4][32]; pad=32*512
    short rt[NGRAN * 8];       // library row per (granule, jj), -1 = pad
    int nq[4];
};

constexpr Sched make_sched() {
    Sched s{};
    short gi[NGP] = {}, gj[NGP] = {};
    char gt[NGP] = {}, gq[NGP] = {};
    int tidx[32][32] = {}, pidx[32] = {};
    {
        int n = 0;
        for (int a = 0; a < 32; ++a)
            for (int b = a; b < 32; ++b) { tidx[a][b] = n; n += 32 - b; }
        for (int i = 0; i < 32; ++i) pidx[i] = i * 32 - i * (i - 1) / 2;
    }
    int g = 0;
    for (int q = 0; q < 4; ++q) {
        int g0 = g;
        // triples (a<=b): granule covers k in [8q,8q+8) for k>=b -> b>>3 <= q
        for (int b = 0; b < 32; ++b)
            if ((b >> 3) <= q)
                for (int a = 0; a <= b; ++a) { gi[g]=(short)a; gj[g]=(short)b; gt[g]=0; gq[g]=(char)q; ++g; }
        // pairs (b,32): theta = z_b*z_k, valid k<=b -> b>>3 >= q
        for (int b = 0; b < 32; ++b)
            if ((b >> 3) >= q) { gi[g]=(short)b; gj[g]=32; gt[g]=1; gq[g]=(char)q; ++g; }
        // linear: theta = z_k
        gi[g]=32; gj[g]=32; gt[g]=2; gq[g]=(char)q; ++g;
        // pad quarter to a multiple of 8 granules (4 chunks)
        while ((g - g0) & 7) { gi[g]=32; gj[g]=32; gt[g]=3; gq[g]=(char)q; ++g; }
        s.nq[q] = (g - g0) / 2;
    }
    for (int gg = 0; gg < NGRAN; ++gg) {
        s.mg[gg] = ((unsigned)gi[gg] * 512u) | (((unsigned)gj[gg] * 512u) << 16);
        int i = gi[gg], j = gj[gg], ty = gt[gg], q = gq[gg];
        for (int jj = 0; jj < 8; ++jj) {
            int k = 8 * q + jj, row = -1;
            if (ty == 0)      { if (k >= j) row = 561 + tidx[i][j] + (k - j); }   // triple (i,j,k)
            else if (ty == 1) { if (k <= i) row = 33 + pidx[k] + (i - k); }       // pair (k,i)
            else if (ty == 2) { row = 1 + k; }                                    // linear z_k
            s.rt[gg * 8 + jj] = (short)row;
        }
    }
    // [NGRAN,NGP): mg stays 0 -> pipeline overreads hit zs[0][0][m], never used
    return s;
}
constexpr Sched S = make_sched();
static_assert(S.nq[0] == 36 && S.nq[1] == 84 && S.nq[2] == 160 && S.nq[3] == 272, "chunk counts");

// ---- prep (R7-proven structure): coalesced, block per 4 granules; B -> fp16 RNE ----
__global__ void sindy_prep(const float* __restrict__ Xi,
                           const float* __restrict__ Xi_mask,
                           uint2* __restrict__ Bp2, size_t ws_size) {
    __shared__ unsigned short sh[8][32];
    const int tid = threadIdx.x;
    const int jj = tid >> 5, n = tid & 31;
#pragma unroll
    for (int pass = 0; pass < 4; ++pass) {
        int g = blockIdx.x * 4 + pass;
        int row = S.rt[g * 8 + jj];
        float f = 0.0f;
        if (row >= 0) f = Xi[row * Z + n] * Xi_mask[row * Z + n];
        _Float16 hh = (_Float16)f;                       // RNE f32->f16
        sh[jj][n] = __builtin_bit_cast(unsigned short, hh);
        __syncthreads();
        if (tid < 64) {
            int n2 = tid & 31, rep = tid >> 5;
            unsigned v0 = sh[4*rep+0][n2], v1 = sh[4*rep+1][n2];
            unsigned v2 = sh[4*rep+2][n2], v3 = sh[4*rep+3][n2];
            int c = g >> 1, h = g & 1;
            size_t idx = ((size_t)c * 64 + h * 32 + n2) * 2 + rep;
            if ((idx + 1) * 8 <= ws_size)
                Bp2[idx] = uint2{v0 | (v1 << 16), v2 | (v3 << 16)};
        }
        __syncthreads();
    }
}

// ---- main: block = 4 tiles x 4 k-splits; wave = ALL 4 tiles, one k-split ----
__global__ __launch_bounds__(256, 2) void sindy_mfma(const float* __restrict__ z,
                                                     const float* __restrict__ Xi,
                                                     const float* __restrict__ Xi_mask,
                                                     const uint4* __restrict__ Bp,
                                                     float* __restrict__ out) {
    const int lane = threadIdx.x & 63;
    const int kh = threadIdx.x >> 6;     // k-split 0..3 (= wave id)
    const int m = lane & 31;
    const int half = lane >> 5;
    const long R = (long)blockIdx.x * 128;  // rows: 4 tiles of 32

    __shared__ float zs[33][4][32];      // interleaved: zs[k][tile][m]; bank = m
    __shared__ float cs[4][32][32];      // sequential-add combine (4 tiles)
    __shared__ unsigned mg_sh[NGP];

    for (int t = threadIdx.x; t < NGP; t += 256) mg_sh[t] = S.mg[t];
    // stage z for 128 rows (coalesced float4 reads)
    for (int idx = threadIdx.x; idx < 1024; idx += 256) {
        int row = idx >> 3, q4 = idx & 7;
        float4 v = ((const float4*)(z + (R + row) * Z))[q4];
        int t = row >> 5, mm = row & 31;
        zs[4*q4+0][t][mm] = v.x; zs[4*q4+1][t][mm] = v.y;
        zs[4*q4+2][t][mm] = v.z; zs[4*q4+3][t][mm] = v.w;
    }
    if (threadIdx.x < 128) zs[32][threadIdx.x >> 5][threadIdx.x & 31] = 1.0f;  // z~[32]=1
    __syncthreads();

    const int c0 = kh * 138;
    const char* zmb = (const char*)&zs[0][0][0] + 4 * m;   // tile t at +128*t
    const unsigned* mgh = mg_sh + half;
    const uint4* bpl = Bp + lane;

    // products for one mg word, all 4 tiles
    auto zprod4 = [&](unsigned ws, float& t0, float& t1, float& t2, float& t3) {
        const char* bi = zmb + (ws & 0xFFFFu);
        const char* bj = zmb + (ws >> 16);
        t0 = *(const float*)(bi +   0) * *(const float*)(bj +   0);
        t1 = *(const float*)(bi + 128) * *(const float*)(bj + 128);
        t2 = *(const float*)(bi + 256) * *(const float*)(bj + 256);
        t3 = *(const float*)(bi + 384) * *(const float*)(bj + 384);
    };

    // B register pipeline, depth 2 bodies x 2 chunks (4 chunks in flight)
    uint4 b00 = bpl[(size_t)(c0 + 0) * 64], b01 = bpl[(size_t)(c0 + 1) * 64];
    uint4 b10 = bpl[(size_t)(c0 + 2) * 64], b11 = bpl[(size_t)(c0 + 3) * 64];

    // marching pointers (strength-reduced; no clamps in the loop)
    const uint4* bptr = bpl + (size_t)(c0 + 4) * 64;   // chunks c+4,c+5 (imm 0/1024)
    const unsigned* mgp = mgh + 2 * c0 + 8;            // mg for body+2

    // prime: products for chunks c0,c0+1; mg words for c0+2,c0+3
    float pa0, pa1, pa2, pa3, pb0, pb1, pb2, pb3;
    {
        unsigned u0 = mgh[2*c0+0], u1 = mgh[2*c0+2];
        zprod4(u0, pa0, pa1, pa2, pa3);
        zprod4(u1, pb0, pb1, pb2, pb3);
    }
    unsigned w0s = mgh[2*c0+4], w1s = mgh[2*c0+6];

    f32x16 acc0 = {}, acc1 = {}, acc2 = {}, acc3 = {};

    auto seg = [&](int Q, int cbeg, int cfin, bool tail) {
        // this quarter's z octets for all 4 tiles, pre-packed to fp16 pairs
        // (RTZ). reg q: lo=k 2q, hi=k 2q+1; k stride 512B, tile stride 128B.
        const char* zq = zmb + Q * 4096;
        h2 zt0_0, zt0_1, zt0_2, zt0_3, zt1_0, zt1_1, zt1_2, zt1_3;
        h2 zt2_0, zt2_1, zt2_2, zt2_3, zt3_0, zt3_1, zt3_2, zt3_3;
        {
#define LDZ(t) \
            { float a0 = *(const float*)(zq + (t)*128 +    0), a1 = *(const float*)(zq + (t)*128 +  512); \
              float a2 = *(const float*)(zq + (t)*128 + 1024), a3 = *(const float*)(zq + (t)*128 + 1536); \
              float a4 = *(const float*)(zq + (t)*128 + 2048), a5 = *(const float*)(zq + (t)*128 + 2560); \
              float a6 = *(const float*)(zq + (t)*128 + 3072), a7 = *(const float*)(zq + (t)*128 + 3584); \
              zt##t##_0 = pkrtz(a0, a1); zt##t##_1 = pkrtz(a2, a3); \
              zt##t##_2 = pkrtz(a4, a5); zt##t##_3 = pkrtz(a6, a7); }
            LDZ(0) LDZ(1) LDZ(2) LDZ(3)
#undef LDZ
        }

#define MKMFMA(t, accv) \
        auto mfma##t = [&](float pp, const uint4& bv) { \
            h2 p2 = pkrtz(pp, pp); \
            union { h2 h[4]; h8 v; } a; \
            a.h[0] = p2 * zt##t##_0; a.h[1] = p2 * zt##t##_1; \
            a.h[2] = p2 * zt##t##_2; a.h[3] = p2 * zt##t##_3; \
            union { uint4 v; h8 h; } b; b.v = bv; \
            accv = __builtin_amdgcn_mfma_f32_32x32x16_f16(a.v, b.h, accv, 0, 0, 0); \
        };
        MKMFMA(0, acc0) MKMFMA(1, acc1) MKMFMA(2, acc2) MKMFMA(3, acc3)
#undef MKMFMA

        const int cend = tail ? cfin - 4 : cfin;
#pragma unroll 2
        for (int c = cbeg; c < cend; c += 2) {
            // top: issue loads for chunks c+4,c+5 — 2 bodies ahead.
            uint4 n0 = bptr[0], n1 = bptr[64];
            bptr += 128;
            // mg for body+2 (pad absorbs overread)
            unsigned nw0 = mgp[0], nw1 = mgp[2];
            mgp += 4;
            // z reads + products for body+1 (4 tiles x 2 chunks)
            float qa0, qa1, qa2, qa3, qb0, qb1, qb2, qb3;
            zprod4(w0s, qa0, qa1, qa2, qa3);
            zprod4(w1s, qb0, qb1, qb2, qb3);
            // 8 MFMAs: 2 chunks x 4 tiles, B shared per chunk
            mfma0(pa0, b00); mfma1(pa1, b00); mfma2(pa2, b00); mfma3(pa3, b00);
            mfma0(pb0, b01); mfma1(pb1, b01); mfma2(pb2, b01); mfma3(pb3, b01);
            // retire products + mg + rotate B pipeline
            pa0 = qa0; pa1 = qa1; pa2 = qa2; pa3 = qa3;
            pb0 = qb0; pb1 = qb1; pb2 = qb2; pb3 = qb3;
            w0s = nw0; w1s = nw1;
            b00 = b10; b01 = b11; b10 = n0; b11 = n1;
        }
        if (tail) {
            // peel body cfin-4 (chunks 548/549): no loads/mg; KEEP z staging
            float qa0, qa1, qa2, qa3, qb0, qb1, qb2, qb3;
            zprod4(w0s, qa0, qa1, qa2, qa3);
            zprod4(w1s, qb0, qb1, qb2, qb3);
            mfma0(pa0, b00); mfma1(pa1, b00); mfma2(pa2, b00); mfma3(pa3, b00);
            mfma0(pb0, b01); mfma1(pb1, b01); mfma2(pb2, b01); mfma3(pb3, b01);
            pa0 = qa0; pa1 = qa1; pa2 = qa2; pa3 = qa3;
            pb0 = qb0; pb1 = qb1; pb2 = qb2; pb3 = qb3;
            b00 = b10; b01 = b11;
            // peel final body cfin-2 (chunks 550/551): consume-only
            mfma0(pa0, b00); mfma1(pa1, b00); mfma2(pa2, b00); mfma3(pa3, b00);
            mfma0(pb0, b01); mfma1(pb1, b01); mfma2(pb2, b01); mfma3(pb3, b01);
        }
    };

    // quarter-aligned pieces of this wave's [c0, c0+138) range (all even)
    if (kh == 0)      { seg(0,   0,  36, false); seg(1,  36, 120, false); seg(2, 120, 138, false); }
    else if (kh == 1) { seg(2, 138, 276, false); }
    else if (kh == 2) { seg(2, 276, 280, false); seg(3, 280, 414, false); }
    else              { seg(3, 414, 552, true); }

    // sequential-add combine: kh3 writes, kh2/kh1 add, kh0 finishes
    if (kh == 3) {
#pragma unroll
        for (int r = 0; r < 16; ++r) {
            int row = (r & 3) + 8 * (r >> 2) + 4 * half;
            cs[0][row][m] = acc0[r]; cs[1][row][m] = acc1[r];
            cs[2][row][m] = acc2[r]; cs[3][row][m] = acc3[r];
        }
    }
    __syncthreads();
    if (kh == 2) {
#pragma unroll
        for (int r = 0; r < 16; ++r) {
            int row = (r & 3) + 8 * (r >> 2) + 4 * half;
            cs[0][row][m] += acc0[r]; cs[1][row][m] += acc1[r];
            cs[2][row][m] += acc2[r]; cs[3][row][m] += acc3[r];
        }
    }
    __syncthreads();
    if (kh == 1) {
#pragma unroll
        for (int r = 0; r < 16; ++r) {
            int row = (r & 3) + 8 * (r >> 2) + 4 * half;
            cs[0][row][m] += acc0[r]; cs[1][row][m] += acc1[r];
            cs[2][row][m] += acc2[r]; cs[3][row][m] += acc3[r];
        }
    }
    __syncthreads();
    if (kh == 0) {
        const float bias = Xi[m] * Xi_mask[m];   // library row 0 (ones), col n = m
#pragma unroll
        for (int r = 0; r < 16; ++r) {
            int row = (r & 3) + 8 * (r >> 2) + 4 * half;
            out[(R +  0 + row) * Z + m] = acc0[r] + cs[0][row][m] + bias;
            out[(R + 32 + row) * Z + m] = acc1[r] + cs[1][row][m] + bias;
            out[(R + 64 + row) * Z + m] = acc2[r] + cs[2][row][m] + bias;
            out[(R + 96 + row) * Z + m] = acc3[r] + cs[3][row][m] + bias;
        }
    }
}

extern "C" void kernel_launch(void* const* d_in, const int* in_sizes, int n_in,
                              void* d_out, int out_size, void* d_ws, size_t ws_size,
                              hipStream_t stream) {
    const float* z       = (const float*)d_in[0];
    const float* Xi      = (const float*)d_in[1];
    const float* Xi_mask = (const float*)d_in[2];
    // d_in[3]=z_mean, d_in[4]=z_std: unused by the reference
    float* out = (float*)d_out;
    uint4* Bp  = (uint4*)d_ws;   // NCHUNK*64*16 = 565,248 bytes

    sindy_prep<<<NGRAN / 4, 256, 0, stream>>>(Xi, Xi_mask, (uint2*)d_ws, ws_size);
    sindy_mfma<<<NBLK, 256, 0, stream>>>(z, Xi, Xi_mask, Bp, out);
}